// Round 11
// baseline (858.171 us; speedup 1.0000x reference)
//
#include <hip/hip_runtime.h>
#include <cstdint>

#define D 128
#define P 8
#define L 3
#define BINS 256

typedef __attribute__((ext_vector_type(8))) _Float16 f16x8;
typedef __attribute__((ext_vector_type(4))) float    f32x4;

// row_ptr[r] = lower_bound(edge_row, r); edge_row is sorted.
__global__ void build_row_ptr(const int* __restrict__ er, int* __restrict__ rp, int n, int e) {
    int r = blockIdx.x * blockDim.x + threadIdx.x;
    if (r > n) return;
    int lo = 0, hi = e;
    while (lo < hi) {
        int mid = (lo + hi) >> 1;
        if (er[mid] < r) lo = mid + 1; else hi = mid;
    }
    rp[r] = lo;
}

// ---- degree-sorted permutation (counting sort, descending degree) ----
__global__ void zero_hist(int* __restrict__ hist) {
    hist[threadIdx.x] = 0;
}
__global__ void hist_deg(const int* __restrict__ rp, int* __restrict__ hist, int n) {
    int r = blockIdx.x * blockDim.x + threadIdx.x;
    if (r >= n) return;
    int d = min(rp[r + 1] - rp[r], BINS - 1);
    atomicAdd(&hist[(BINS - 1) - d], 1);   // descending degree
}
__global__ void scan_hist(int* __restrict__ hist) {   // 1 block, BINS threads
    __shared__ int a[BINS], b[BINS];
    int t = threadIdx.x;
    int orig = hist[t];
    a[t] = orig;
    __syncthreads();
    int* src = a; int* dst = b;
    for (int off = 1; off < BINS; off <<= 1) {
        dst[t] = src[t] + ((t >= off) ? src[t - off] : 0);
        __syncthreads();
        int* tmp = src; src = dst; dst = tmp;
    }
    hist[t] = src[t] - orig;   // exclusive scan
}
__global__ void build_perm(const int* __restrict__ rp, int* __restrict__ hist,
                           int* __restrict__ perm, int n) {
    int r = blockIdx.x * blockDim.x + threadIdx.x;
    if (r >= n) return;
    int d = min(rp[r + 1] - rp[r], BINS - 1);
    int pos = atomicAdd(&hist[(BINS - 1) - d], 1);
    perm[pos] = r;
}

// ww = softmax-contracted weights, fp16, MFMA B-fragment layout:
// wwB[l][kt][o][k']  (i = kt*32 + k'); b-frag load is 16B contiguous.
__global__ void build_ww(const float* __restrict__ sp, const float* __restrict__ lw,
                         _Float16* __restrict__ wwB) {
    int idx = blockIdx.x * blockDim.x + threadIdx.x;
    if (idx >= L * D * D) return;
    int l = idx / (D * D);
    int rem = idx - l * D * D;
    int o = rem / D;
    int i = rem - o * D;
    float wv[P];
    float m = -1e30f;
#pragma unroll
    for (int p = 0; p < P; p++) { wv[p] = lw[l * P + p]; m = fmaxf(m, wv[p]); }
    float s = 0.f;
#pragma unroll
    for (int p = 0; p < P; p++) { wv[p] = __expf(wv[p] - m); s += wv[p]; }
    float inv = 1.0f / s;
    const float* spp = sp + ((size_t)(l * D + o) * D + i) * P;
    float acc = 0.f;
#pragma unroll
    for (int p = 0; p < P; p++) acc += spp[p] * wv[p];
    int kt = i >> 5, kp = i & 31;
    wwB[(((l * 4 + kt) * D + o) << 5) + kp] = (_Float16)(acc * inv);
}

// MFMA on a 16x128 fp16 staged tile: 8 output col-tiles split 2-per-wave.
// Output rows scattered via perm (prow[i] = global row of tile slot i, or -1).
static __device__ __forceinline__ void mfma_store16p(const _Float16 (*s_h)[136],
                                                     const _Float16* __restrict__ wwB_l,
                                                     _Float16* __restrict__ y,
                                                     const int* __restrict__ perm,
                                                     int row0, int n, int tid) {
    const int w = tid >> 6, lane = tid & 63;
    const int quad = lane >> 4, l16 = lane & 15;
    f32x4 acc[2] = {};
#pragma unroll
    for (int kt = 0; kt < 4; kt++) {
        f16x8 af = *(const f16x8*)&s_h[l16][kt * 32 + quad * 8];
#pragma unroll
        for (int c = 0; c < 2; c++) {
            const int ct = w * 2 + c;
            f16x8 bf = *(const f16x8*)&wwB_l[((kt * D + ct * 16 + l16) << 5) + quad * 8];
            acc[c] = __builtin_amdgcn_mfma_f32_16x16x32_f16(af, bf, acc[c], 0, 0, 0);
        }
    }
    // C/D layout: col = lane&15, row = quad*4 + reg (m89-verified)
#pragma unroll
    for (int c = 0; c < 2; c++) {
        const int ct = w * 2 + c;
#pragma unroll
        for (int rg = 0; rg < 4; rg++) {
            int idx = row0 + quad * 4 + rg;
            if (idx < n) {
                int row = perm[idx];
                y[row * D + ct * 16 + l16] = (_Float16)acc[c][rg];
            }
        }
    }
}

// Y1 = cast_f16(x) * W0  (natural row order; dense, no imbalance). 16-row tiles.
__global__ __launch_bounds__(256, 8)
void gemm_x32(const float* __restrict__ x, const _Float16* __restrict__ wwB_l,
              _Float16* __restrict__ y, int n) {
    __shared__ _Float16 s_h[16][136];
    const int tid = threadIdx.x;
    const int row0 = blockIdx.x * 16;
    const int c8 = (tid & 15) * 8;
    {
        int r = tid >> 4;
        int row = row0 + r;
        float4 v0 = {}, v1 = {};
        if (row < n) {
            v0 = *(const float4*)&x[row * D + c8];
            v1 = *(const float4*)&x[row * D + c8 + 4];
        }
        f16x8 h;
        h[0] = (_Float16)v0.x; h[1] = (_Float16)v0.y;
        h[2] = (_Float16)v0.z; h[3] = (_Float16)v0.w;
        h[4] = (_Float16)v1.x; h[5] = (_Float16)v1.y;
        h[6] = (_Float16)v1.z; h[7] = (_Float16)v1.w;
        *(f16x8*)&s_h[r][c8] = h;
    }
    __syncthreads();

    // natural-order store (identity perm path inlined)
    const int w = tid >> 6, lane = tid & 63;
    const int quad = lane >> 4, l16 = lane & 15;
    f32x4 acc[2] = {};
#pragma unroll
    for (int kt = 0; kt < 4; kt++) {
        f16x8 af = *(const f16x8*)&s_h[l16][kt * 32 + quad * 8];
#pragma unroll
        for (int c = 0; c < 2; c++) {
            const int ct = w * 2 + c;
            f16x8 bf = *(const f16x8*)&wwB_l[((kt * D + ct * 16 + l16) << 5) + quad * 8];
            acc[c] = __builtin_amdgcn_mfma_f32_16x16x32_f16(af, bf, acc[c], 0, 0, 0);
        }
    }
#pragma unroll
    for (int c = 0; c < 2; c++) {
        const int ct = w * 2 + c;
#pragma unroll
        for (int rg = 0; rg < 4; rg++) {
            int row = row0 + quad * 4 + rg;
            if (row < n) y[row * D + ct * 16 + l16] = (_Float16)acc[c][rg];
        }
    }
}

// gather-accumulate core: branch-free, 8-deep batched loads
static __device__ __forceinline__ void gather_row(float (&a)[8],
                                                  const _Float16* __restrict__ y,
                                                  const int* __restrict__ col,
                                                  const float* __restrict__ vals,
                                                  int e, int e1, int c8) {
    union U8 { uint4 u; _Float16 h[8]; };
    for (; e + 8 <= e1; e += 8) {
        int c[8]; float v[8]; U8 g[8];
#pragma unroll
        for (int j = 0; j < 8; j++) { c[j] = col[e + j]; v[j] = vals[e + j]; }
#pragma unroll
        for (int j = 0; j < 8; j++) g[j].u = *(const uint4*)&y[c[j] * D + c8];
#pragma unroll
        for (int j = 0; j < 8; j++)
#pragma unroll
            for (int k = 0; k < 8; k++) a[k] += v[j] * (float)g[j].h[k];
    }
    for (; e + 4 <= e1; e += 4) {
        int c[4]; float v[4]; U8 g[4];
#pragma unroll
        for (int j = 0; j < 4; j++) { c[j] = col[e + j]; v[j] = vals[e + j]; }
#pragma unroll
        for (int j = 0; j < 4; j++) g[j].u = *(const uint4*)&y[c[j] * D + c8];
#pragma unroll
        for (int j = 0; j < 4; j++)
#pragma unroll
            for (int k = 0; k < 8; k++) a[k] += v[j] * (float)g[j].h[k];
    }
    for (; e < e1; e++) {
        U8 g; g.u = *(const uint4*)&y[col[e] * D + c8];
        float v = vals[e];
#pragma unroll
        for (int k = 0; k < 8; k++) a[k] += v * (float)g.h[k];
    }
}

// Fused layer: Y_next = relu(adj * Y_prev) * W.  16 equal-degree rows per
// block via perm -> barrier wait ~0; gather loop branch-free (round-9 core).
__global__ __launch_bounds__(256, 8)
void fused_layer(const _Float16* __restrict__ yprev, const int* __restrict__ rp,
                 const int* __restrict__ col, const float* __restrict__ vals,
                 const int* __restrict__ perm,
                 const _Float16* __restrict__ wwB_l, _Float16* __restrict__ ynext, int n) {
    __shared__ _Float16 s_h[16][136];
    const int tid = threadIdx.x;
    const int row0 = blockIdx.x * 16;
    const int sg = tid >> 4;          // 0..15, one row per subgroup
    const int c8 = (tid & 15) * 8;
    {
        int idx = row0 + sg;
        float a[8] = {0.f, 0.f, 0.f, 0.f, 0.f, 0.f, 0.f, 0.f};
        if (idx < n) {
            int r = perm[idx];
            gather_row(a, yprev, col, vals, rp[r], rp[r + 1], c8);
        }
        f16x8 o;
#pragma unroll
        for (int k = 0; k < 8; k++) o[k] = (_Float16)fmaxf(a[k], 0.f);
        *(f16x8*)&s_h[sg][c8] = o;
    }
    __syncthreads();
    mfma_store16p(s_h, wwB_l, ynext, perm, row0, n, tid);
}

// Final: out = adj * Y3, fp32 out. perm for tail balance; no barrier.
__global__ __launch_bounds__(256, 8)
void spmm_f32(const _Float16* __restrict__ y, const int* __restrict__ rp,
              const int* __restrict__ col, const float* __restrict__ vals,
              const int* __restrict__ perm, float* __restrict__ out, int n) {
    const int tid = threadIdx.x;
    const int idx = blockIdx.x * 16 + (tid >> 4);
    const int c8 = (tid & 15) * 8;
    if (idx >= n) return;
    const int r = perm[idx];
    float a[8] = {0.f, 0.f, 0.f, 0.f, 0.f, 0.f, 0.f, 0.f};
    gather_row(a, y, col, vals, rp[r], rp[r + 1], c8);
    *(float4*)&out[r * D + c8]     = make_float4(a[0], a[1], a[2], a[3]);
    *(float4*)&out[r * D + c8 + 4] = make_float4(a[4], a[5], a[6], a[7]);
}

extern "C" void kernel_launch(void* const* d_in, const int* in_sizes, int n_in,
                              void* d_out, int out_size, void* d_ws, size_t ws_size,
                              hipStream_t stream) {
    const int*   edge_row  = (const int*)d_in[0];
    const int*   edge_col  = (const int*)d_in[1];
    const float* edge_vals = (const float*)d_in[2];
    const float* x         = (const float*)d_in[3];
    const float* sp        = (const float*)d_in[4];
    const float* lw        = (const float*)d_in[5];
    float* out = (float*)d_out;

    const int E_ = in_sizes[0];
    const int N_ = in_sizes[3] / D;

    // Workspace: row_ptr | hist | perm | wwB (fp16 frag) | bufA | bufB
    char* ws = (char*)d_ws;
    int* row_ptr = (int*)ws;
    size_t off = (((size_t)(N_ + 1) * sizeof(int)) + 255) & ~(size_t)255;
    int* hist = (int*)(ws + off);
    off += (size_t)BINS * sizeof(int);
    int* perm = (int*)(ws + off);
    off = ((off + (size_t)N_ * sizeof(int)) + 255) & ~(size_t)255;
    _Float16* wwB = (_Float16*)(ws + off);
    off += (size_t)L * 4 * D * 32 * sizeof(_Float16);
    off = (off + 255) & ~(size_t)255;
    _Float16* bufA = (_Float16*)(ws + off);
    off += (size_t)N_ * D * sizeof(_Float16);
    _Float16* bufB = (_Float16*)(ws + off);

    const int nb = (N_ + 255) / 256;
    build_row_ptr<<<(N_ + 1 + 255) / 256, 256, 0, stream>>>(edge_row, row_ptr, N_, E_);
    zero_hist<<<1, BINS, 0, stream>>>(hist);
    hist_deg<<<nb, 256, 0, stream>>>(row_ptr, hist, N_);
    scan_hist<<<1, BINS, 0, stream>>>(hist);
    build_perm<<<nb, 256, 0, stream>>>(row_ptr, hist, perm, N_);
    build_ww<<<(L * D * D + 255) / 256, 256, 0, stream>>>(sp, lw, wwB);

    const int sblk = (N_ + 15) / 16;
    const int WWL = 4 * D * 32;   // per-layer wwB stride

    // Y1 = x*W0 ; Y2 = relu(adj*Y1)*W1 ; Y3 = relu(adj*Y2)*W2 ; out = adj*Y3
    gemm_x32<<<sblk, 256, 0, stream>>>(x, wwB, bufA, N_);
    fused_layer<<<sblk, 256, 0, stream>>>(bufA, row_ptr, edge_col, edge_vals, perm,
                                          wwB + WWL,     bufB, N_);
    fused_layer<<<sblk, 256, 0, stream>>>(bufB, row_ptr, edge_col, edge_vals, perm,
                                          wwB + 2 * WWL, bufA, N_);
    spmm_f32<<<sblk, 256, 0, stream>>>(bufA, row_ptr, edge_col, edge_vals, perm, out, N_);
}

// Round 12
// 344.758 us; speedup vs baseline: 2.4892x; 2.4892x over previous
//
#include <hip/hip_runtime.h>
#include <cstdint>

#define D 128
#define P 8
#define L 3
#define BINS 256

typedef __attribute__((ext_vector_type(8))) _Float16 f16x8;
typedef __attribute__((ext_vector_type(4))) float    f32x4;

// row_ptr[r] = lower_bound(edge_row, r); edge_row is sorted.
__global__ void build_row_ptr(const int* __restrict__ er, int* __restrict__ rp, int n, int e) {
    int r = blockIdx.x * blockDim.x + threadIdx.x;
    if (r > n) return;
    int lo = 0, hi = e;
    while (lo < hi) {
        int mid = (lo + hi) >> 1;
        if (er[mid] < r) lo = mid + 1; else hi = mid;
    }
    rp[r] = lo;
}

// ---- degree-sorted permutation: two-level counting sort (no atomic storms) ----
__global__ void zero_hist(int* __restrict__ ghist) {
    ghist[threadIdx.x] = 0;
}

// Per-block LDS histogram; local rank per row; one aggregated global atomic
// per (block, bin) reserves this block's chunk within the bin.
__global__ void count_rows(const int* __restrict__ rp, int* __restrict__ ghist,
                           int* __restrict__ lrank, int* __restrict__ bbase, int n) {
    __shared__ int lh[BINS];
    const int t = threadIdx.x;
    lh[t] = 0;
    __syncthreads();
    const int r = blockIdx.x * 256 + t;
    if (r < n) {
        int d = min(rp[r + 1] - rp[r], BINS - 1);
        int bin = (BINS - 1) - d;                 // descending degree
        lrank[r] = atomicAdd(&lh[bin], 1);        // LDS atomic: cheap
    }
    __syncthreads();
    int c = lh[t];
    if (c > 0) bbase[blockIdx.x * BINS + t] = atomicAdd(&ghist[t], c);
}

// Exclusive scan of ghist -> binstart (1 block, BINS threads).
__global__ void scan_hist(const int* __restrict__ ghist, int* __restrict__ binstart) {
    __shared__ int a[BINS], b[BINS];
    int t = threadIdx.x;
    int orig = ghist[t];
    a[t] = orig;
    __syncthreads();
    int* src = a; int* dst = b;
    for (int off = 1; off < BINS; off <<= 1) {
        dst[t] = src[t] + ((t >= off) ? src[t - off] : 0);
        __syncthreads();
        int* tmp = src; src = dst; dst = tmp;
    }
    binstart[t] = src[t] - orig;
}

__global__ void scatter_perm(const int* __restrict__ rp, const int* __restrict__ binstart,
                             const int* __restrict__ bbase, const int* __restrict__ lrank,
                             int* __restrict__ perm, int n) {
    const int r = blockIdx.x * 256 + threadIdx.x;
    if (r >= n) return;
    int d = min(rp[r + 1] - rp[r], BINS - 1);
    int bin = (BINS - 1) - d;
    perm[binstart[bin] + bbase[blockIdx.x * BINS + bin] + lrank[r]] = r;
}

// ww = softmax-contracted weights, fp16, MFMA B-fragment layout:
// wwB[l][kt][o][k']  (i = kt*32 + k'); b-frag load is 16B contiguous.
__global__ void build_ww(const float* __restrict__ sp, const float* __restrict__ lw,
                         _Float16* __restrict__ wwB) {
    int idx = blockIdx.x * blockDim.x + threadIdx.x;
    if (idx >= L * D * D) return;
    int l = idx / (D * D);
    int rem = idx - l * D * D;
    int o = rem / D;
    int i = rem - o * D;
    float wv[P];
    float m = -1e30f;
#pragma unroll
    for (int p = 0; p < P; p++) { wv[p] = lw[l * P + p]; m = fmaxf(m, wv[p]); }
    float s = 0.f;
#pragma unroll
    for (int p = 0; p < P; p++) { wv[p] = __expf(wv[p] - m); s += wv[p]; }
    float inv = 1.0f / s;
    const float* spp = sp + ((size_t)(l * D + o) * D + i) * P;
    float acc = 0.f;
#pragma unroll
    for (int p = 0; p < P; p++) acc += spp[p] * wv[p];
    int kt = i >> 5, kp = i & 31;
    wwB[(((l * 4 + kt) * D + o) << 5) + kp] = (_Float16)(acc * inv);
}

// MFMA on a 16x128 fp16 staged tile: 8 output col-tiles split 2-per-wave.
// Output rows scattered via perm.
static __device__ __forceinline__ void mfma_store16p(const _Float16 (*s_h)[136],
                                                     const _Float16* __restrict__ wwB_l,
                                                     _Float16* __restrict__ y,
                                                     const int* __restrict__ perm,
                                                     int row0, int n, int tid) {
    const int w = tid >> 6, lane = tid & 63;
    const int quad = lane >> 4, l16 = lane & 15;
    f32x4 acc[2] = {};
#pragma unroll
    for (int kt = 0; kt < 4; kt++) {
        f16x8 af = *(const f16x8*)&s_h[l16][kt * 32 + quad * 8];
#pragma unroll
        for (int c = 0; c < 2; c++) {
            const int ct = w * 2 + c;
            f16x8 bf = *(const f16x8*)&wwB_l[((kt * D + ct * 16 + l16) << 5) + quad * 8];
            acc[c] = __builtin_amdgcn_mfma_f32_16x16x32_f16(af, bf, acc[c], 0, 0, 0);
        }
    }
    // C/D layout: col = lane&15, row = quad*4 + reg (m89-verified)
#pragma unroll
    for (int c = 0; c < 2; c++) {
        const int ct = w * 2 + c;
#pragma unroll
        for (int rg = 0; rg < 4; rg++) {
            int idx = row0 + quad * 4 + rg;
            if (idx < n) {
                int row = perm[idx];
                y[row * D + ct * 16 + l16] = (_Float16)acc[c][rg];
            }
        }
    }
}

// Y1 = cast_f16(x) * W0  (natural row order; dense, no imbalance). 16-row tiles.
__global__ __launch_bounds__(256, 8)
void gemm_x32(const float* __restrict__ x, const _Float16* __restrict__ wwB_l,
              _Float16* __restrict__ y, int n) {
    __shared__ _Float16 s_h[16][136];
    const int tid = threadIdx.x;
    const int row0 = blockIdx.x * 16;
    const int c8 = (tid & 15) * 8;
    {
        int r = tid >> 4;
        int row = row0 + r;
        float4 v0 = {}, v1 = {};
        if (row < n) {
            v0 = *(const float4*)&x[row * D + c8];
            v1 = *(const float4*)&x[row * D + c8 + 4];
        }
        f16x8 h;
        h[0] = (_Float16)v0.x; h[1] = (_Float16)v0.y;
        h[2] = (_Float16)v0.z; h[3] = (_Float16)v0.w;
        h[4] = (_Float16)v1.x; h[5] = (_Float16)v1.y;
        h[6] = (_Float16)v1.z; h[7] = (_Float16)v1.w;
        *(f16x8*)&s_h[r][c8] = h;
    }
    __syncthreads();

    const int w = tid >> 6, lane = tid & 63;
    const int quad = lane >> 4, l16 = lane & 15;
    f32x4 acc[2] = {};
#pragma unroll
    for (int kt = 0; kt < 4; kt++) {
        f16x8 af = *(const f16x8*)&s_h[l16][kt * 32 + quad * 8];
#pragma unroll
        for (int c = 0; c < 2; c++) {
            const int ct = w * 2 + c;
            f16x8 bf = *(const f16x8*)&wwB_l[((kt * D + ct * 16 + l16) << 5) + quad * 8];
            acc[c] = __builtin_amdgcn_mfma_f32_16x16x32_f16(af, bf, acc[c], 0, 0, 0);
        }
    }
#pragma unroll
    for (int c = 0; c < 2; c++) {
        const int ct = w * 2 + c;
#pragma unroll
        for (int rg = 0; rg < 4; rg++) {
            int row = row0 + quad * 4 + rg;
            if (row < n) y[row * D + ct * 16 + l16] = (_Float16)acc[c][rg];
        }
    }
}

// gather-accumulate core: branch-free, 8-deep batched loads
static __device__ __forceinline__ void gather_row(float (&a)[8],
                                                  const _Float16* __restrict__ y,
                                                  const int* __restrict__ col,
                                                  const float* __restrict__ vals,
                                                  int e, int e1, int c8) {
    union U8 { uint4 u; _Float16 h[8]; };
    for (; e + 8 <= e1; e += 8) {
        int c[8]; float v[8]; U8 g[8];
#pragma unroll
        for (int j = 0; j < 8; j++) { c[j] = col[e + j]; v[j] = vals[e + j]; }
#pragma unroll
        for (int j = 0; j < 8; j++) g[j].u = *(const uint4*)&y[c[j] * D + c8];
#pragma unroll
        for (int j = 0; j < 8; j++)
#pragma unroll
            for (int k = 0; k < 8; k++) a[k] += v[j] * (float)g[j].h[k];
    }
    for (; e + 4 <= e1; e += 4) {
        int c[4]; float v[4]; U8 g[4];
#pragma unroll
        for (int j = 0; j < 4; j++) { c[j] = col[e + j]; v[j] = vals[e + j]; }
#pragma unroll
        for (int j = 0; j < 4; j++) g[j].u = *(const uint4*)&y[c[j] * D + c8];
#pragma unroll
        for (int j = 0; j < 4; j++)
#pragma unroll
            for (int k = 0; k < 8; k++) a[k] += v[j] * (float)g[j].h[k];
    }
    for (; e < e1; e++) {
        U8 g; g.u = *(const uint4*)&y[col[e] * D + c8];
        float v = vals[e];
#pragma unroll
        for (int k = 0; k < 8; k++) a[k] += v * (float)g.h[k];
    }
}

// Fused layer: Y_next = relu(adj * Y_prev) * W.  16 equal-degree rows per
// block via perm -> barrier wait ~0; gather loop branch-free.
__global__ __launch_bounds__(256, 8)
void fused_layer(const _Float16* __restrict__ yprev, const int* __restrict__ rp,
                 const int* __restrict__ col, const float* __restrict__ vals,
                 const int* __restrict__ perm,
                 const _Float16* __restrict__ wwB_l, _Float16* __restrict__ ynext, int n) {
    __shared__ _Float16 s_h[16][136];
    const int tid = threadIdx.x;
    const int row0 = blockIdx.x * 16;
    const int sg = tid >> 4;
    const int c8 = (tid & 15) * 8;
    {
        int idx = row0 + sg;
        float a[8] = {0.f, 0.f, 0.f, 0.f, 0.f, 0.f, 0.f, 0.f};
        if (idx < n) {
            int r = perm[idx];
            gather_row(a, yprev, col, vals, rp[r], rp[r + 1], c8);
        }
        f16x8 o;
#pragma unroll
        for (int k = 0; k < 8; k++) o[k] = (_Float16)fmaxf(a[k], 0.f);
        *(f16x8*)&s_h[sg][c8] = o;
    }
    __syncthreads();
    mfma_store16p(s_h, wwB_l, ynext, perm, row0, n, tid);
}

// Final: out = adj * Y3, fp32 out. perm for tail balance; no barrier.
__global__ __launch_bounds__(256, 8)
void spmm_f32(const _Float16* __restrict__ y, const int* __restrict__ rp,
              const int* __restrict__ col, const float* __restrict__ vals,
              const int* __restrict__ perm, float* __restrict__ out, int n) {
    const int tid = threadIdx.x;
    const int idx = blockIdx.x * 16 + (tid >> 4);
    const int c8 = (tid & 15) * 8;
    if (idx >= n) return;
    const int r = perm[idx];
    float a[8] = {0.f, 0.f, 0.f, 0.f, 0.f, 0.f, 0.f, 0.f};
    gather_row(a, y, col, vals, rp[r], rp[r + 1], c8);
    *(float4*)&out[r * D + c8]     = make_float4(a[0], a[1], a[2], a[3]);
    *(float4*)&out[r * D + c8 + 4] = make_float4(a[4], a[5], a[6], a[7]);
}

extern "C" void kernel_launch(void* const* d_in, const int* in_sizes, int n_in,
                              void* d_out, int out_size, void* d_ws, size_t ws_size,
                              hipStream_t stream) {
    const int*   edge_row  = (const int*)d_in[0];
    const int*   edge_col  = (const int*)d_in[1];
    const float* edge_vals = (const float*)d_in[2];
    const float* x         = (const float*)d_in[3];
    const float* sp        = (const float*)d_in[4];
    const float* lw        = (const float*)d_in[5];
    float* out = (float*)d_out;

    const int E_ = in_sizes[0];
    const int N_ = in_sizes[3] / D;
    const int nb = (N_ + 255) / 256;

    // Workspace: row_ptr | ghist | binstart | lrank | bbase | perm | wwB | bufA | bufB
    char* ws = (char*)d_ws;
    int* row_ptr = (int*)ws;
    size_t off = (((size_t)(N_ + 1) * sizeof(int)) + 255) & ~(size_t)255;
    int* ghist = (int*)(ws + off);      off += (size_t)BINS * sizeof(int);
    int* binstart = (int*)(ws + off);   off += (size_t)BINS * sizeof(int);
    int* lrank = (int*)(ws + off);      off += (size_t)N_ * sizeof(int);
    int* bbase = (int*)(ws + off);      off += (size_t)nb * BINS * sizeof(int);
    int* perm = (int*)(ws + off);       off = ((off + (size_t)N_ * sizeof(int)) + 255) & ~(size_t)255;
    _Float16* wwB = (_Float16*)(ws + off);
    off += (size_t)L * 4 * D * 32 * sizeof(_Float16);
    off = (off + 255) & ~(size_t)255;
    _Float16* bufA = (_Float16*)(ws + off);
    off += (size_t)N_ * D * sizeof(_Float16);
    _Float16* bufB = (_Float16*)(ws + off);

    build_row_ptr<<<(N_ + 1 + 255) / 256, 256, 0, stream>>>(edge_row, row_ptr, N_, E_);
    zero_hist<<<1, BINS, 0, stream>>>(ghist);
    count_rows<<<nb, 256, 0, stream>>>(row_ptr, ghist, lrank, bbase, N_);
    scan_hist<<<1, BINS, 0, stream>>>(ghist, binstart);
    scatter_perm<<<nb, 256, 0, stream>>>(row_ptr, binstart, bbase, lrank, perm, N_);
    build_ww<<<(L * D * D + 255) / 256, 256, 0, stream>>>(sp, lw, wwB);

    const int sblk = (N_ + 15) / 16;
    const int WWL = 4 * D * 32;   // per-layer wwB stride

    // Y1 = x*W0 ; Y2 = relu(adj*Y1)*W1 ; Y3 = relu(adj*Y2)*W2 ; out = adj*Y3
    gemm_x32<<<sblk, 256, 0, stream>>>(x, wwB, bufA, N_);
    fused_layer<<<sblk, 256, 0, stream>>>(bufA, row_ptr, edge_col, edge_vals, perm,
                                          wwB + WWL,     bufB, N_);
    fused_layer<<<sblk, 256, 0, stream>>>(bufB, row_ptr, edge_col, edge_vals, perm,
                                          wwB + 2 * WWL, bufA, N_);
    spmm_f32<<<sblk, 256, 0, stream>>>(bufA, row_ptr, edge_col, edge_vals, perm, out, N_);
}